// Round 21
// baseline (32.882 us; speedup 1.0000x reference)
//
#include <hip/hip_runtime.h>
#include <hip/hip_fp16.h>

#define NGRID 64
#define NEL (NGRID*NGRID*NGRID)   /* 262144 */
#define IDX(i,j,k) ((((i)*64 + (j)) * 64) + (k))

#define NSLAB    16                /* slab = 4 consecutive i-planes = 16384 elements */
#define SLAB_EL  16384
#define NTYPE    256
#define NCHUNK   16                /* chunks per slab, 1024 elements each */
#define CAP      32                /* per-(chunk,type) bucket capacity; mean 4, >10 sigma */

#define RHO_EL   2176              /* k1 rho tile: 2 i-planes x 17 j x 64 k */

/* k5 tile: 4i x 8j x 32k nodes (1024) <- halo box 5x9x33 = 1485 elements */
#define SE       1485
#define K5_LDS   (12*SE*4)         /* 71280 B: dword-major [12][SE] -> 2 blocks/CU */

/* U4h padded layout [i][j][65]: slot k=64 duplicates k=0 -> k4 loads nodes
   (k, k+1) as ONE 16 B read (8 B aligned; dwordx4 needs only dword align). */
#define UPITCH   65
#define U4P_SZ   ((size_t)64*64*UPITCH*8)   /* 2.03 MB */

// ---- workspace layout (bytes) ----
// KUe48: 24 halfs (48 B) per element, natural element order.
// sorted16: ushort slab-local element ids (14 bits) -> half the scatter traffic.
#define WS_U4     0                                   // padded fp16 U, 2.03 MB
#define WS_KUE    (WS_U4 + U4P_SZ)                    // NEL*48 B = 12 MB
#define WS_SORTED (WS_KUE + (size_t)NEL*48)           // 256chunks*256types*CAP u16 = 4 MB
#define WS_CNT    (WS_SORTED + (size_t)256*NTYPE*CAP*2) // [slab][type][chunk16] i32 = 256 KB
#define WS_NEEDED (size_t)(WS_CNT + NSLAB*NTYPE*NCHUNK*4)

typedef unsigned uv4 __attribute__((ext_vector_type(4)));
typedef uv4 uv4_a8 __attribute__((aligned(8)));       // clang: lowers vector alignment

__device__ __forceinline__ int type_of(const float* __restrict__ rho, int i, int j, int k) {
    int i1 = (i + 1) & 63, j1 = (j + 1) & 63, k1 = (k + 1) & 63;
    int t = 0;
    t |= (rho[IDX(i,  j,  k )] > 0.5f ? 1 : 0) << 0;
    t |= (rho[IDX(i1, j,  k )] > 0.5f ? 1 : 0) << 4;
    t |= (rho[IDX(i,  j1, k )] > 0.5f ? 1 : 0) << 2;
    t |= (rho[IDX(i1, j1, k )] > 0.5f ? 1 : 0) << 6;
    t |= (rho[IDX(i,  j,  k1)] > 0.5f ? 1 : 0) << 1;
    t |= (rho[IDX(i1, j,  k1)] > 0.5f ? 1 : 0) << 5;
    t |= (rho[IDX(i,  j1, k1)] > 0.5f ? 1 : 0) << 3;
    t |= (rho[IDX(i1, j1, k1)] > 0.5f ? 1 : 0) << 7;
    return t;
}

// K1: 256 blocks x 1024 thr; slab = b&15, chunk = b>>4 (b%8==slab%8 -> XCD
// pinned). Stage rho bits + contiguous 12 KB U slice (coalesced), type from
// LDS, pack U->fp16 into the PADDED U4h (k==0 thread also fills slot 64),
// LDS hist/rank, scatter slab-local ushort id into the (slab,chunk,type)
// bucket, emit the count row.
__global__ __launch_bounds__(1024) void k1_pack_scatter(
    const float* __restrict__ U, const float* __restrict__ rho,
    uint2* __restrict__ U4hp, unsigned short* __restrict__ sorted16,
    int* __restrict__ cntmat)
{
    __shared__ int lh[NTYPE];
    __shared__ int rb[RHO_EL];     // [2][17][64] occupancy bits
    __shared__ float us[3072];     // block's U slice (1024 el x 3 floats)
    int tid = threadIdx.x;
    int b = blockIdx.x;
    int slab = b & 15, chunk = b >> 4;
    int i  = slab * 4 + (chunk >> 2);
    int j0 = (chunk & 3) << 4;
    if (tid < NTYPE) lh[tid] = 0;

    int base = slab * SLAB_EL + chunk * 1024;
    if (tid < 768)                 // 768 float4 = 12 KB, fully coalesced
        ((float4*)us)[tid] = ((const float4*)(U + (size_t)base * 3))[tid];

    for (int f = tid; f < RHO_EL; f += 1024) {
        int pi = (f >= 1088) ? 1 : 0;        // plane: 0 -> i, 1 -> i+1
        int rem = f - pi * 1088;
        int pj = rem >> 6, kk = rem & 63;
        int ei = (i + pi) & 63;
        int ej = (j0 + pj) & 63;
        rb[f] = rho[IDX(ei, ej, kk)] > 0.5f ? 1 : 0;
    }
    __syncthreads();

    int e = base + tid;
    int k = tid & 63, jj = tid >> 6;         // element = (i, j0+jj, k)
    union { __half2 h; unsigned u; } pxy, pz;
    pxy.h = __floats2half2_rn(us[3*tid + 0], us[3*tid + 1]);
    pz.h  = __floats2half2_rn(us[3*tid + 2], 0.0f);
    int uidx = (i * 64 + (j0 + jj)) * UPITCH + k;
    U4hp[uidx] = make_uint2(pxy.u, pz.u);
    if (k == 0) U4hp[uidx + 64] = make_uint2(pxy.u, pz.u);   // wrap duplicate

    int t = 0;
    #pragma unroll
    for (int di = 0; di < 2; ++di)
        #pragma unroll
        for (int dj = 0; dj < 2; ++dj)
            #pragma unroll
            for (int dk = 0; dk < 2; ++dk)
                t |= rb[di*1088 + (jj + dj)*64 + ((k + dk) & 63)] << (di*4 + dj*2 + dk);

    int rank = atomicAdd(&lh[t], 1);         // LDS-only atomic
    if (rank < CAP)                          // overflow ~impossible (mean 4)
        sorted16[((slab * NCHUNK + chunk) * NTYPE + t) * CAP + rank] =
            (unsigned short)(e - slab * SLAB_EL);   // slab-local 14-bit id
    __syncthreads();
    if (tid < NTYPE)
        cntmat[(slab * NTYPE + tid) * NCHUNK + chunk] = lh[tid];
}

// K4: 1024 blocks x 512 thr (8 waves). Wave = (slab, type, half<64>).
// Count row broadcast; lane locates its element among the 16 chunk-fragments.
// 4 x 16 B k-pair gathers from padded U4h; per-corner row-compute; 24 halfs
// -> 3 dwordx4 stores (48 B). readfirstlane type -> s_load filter path.
__global__ __launch_bounds__(512) void k4_apply(
    const uint2* __restrict__ U4hp, const float* __restrict__ filters,
    const unsigned short* __restrict__ sorted16, const int* __restrict__ cntmat,
    uint4* __restrict__ KUe48)
{
    int b = blockIdx.x;                       // 1024 blocks
    int slab = (b & 7) + 8 * (b >> 9);        // XCD-pinned
    int mid  = (b >> 3) & 63;                 // 64 blocks/slab
    int w    = threadIdx.x >> 6;              // wave 0..7
    int unit = mid * 8 + w;                   // 512 units/slab = 256 types x 2
    int tt   = __builtin_amdgcn_readfirstlane(unit >> 1);
    int h    = unit & 1;                      // half: elements [h*64, h*64+64)

    const int4* crow = (const int4*)(cntmat + (slab * NTYPE + tt) * NCHUNK);
    int4 c0 = crow[0], c1 = crow[1], c2 = crow[2], c3 = crow[3];
    int c[16] = { c0.x,c0.y,c0.z,c0.w, c1.x,c1.y,c1.z,c1.w,
                  c2.x,c2.y,c2.z,c2.w, c3.x,c3.y,c3.z,c3.w };
    int total = 0;
    #pragma unroll
    for (int f = 0; f < 16; ++f) total += c[f];
    total = __builtin_amdgcn_readfirstlane(total);
    if (total <= h * 64) return;              // whole wave empty

    int g = h * 64 + ((int)threadIdx.x & 63);
    const float* __restrict__ F = filters + tt * 576;   // SGPR base -> s_load

    if (g < total) {
        int acc = 0, frag = 0, off = 0;
        bool found = false;
        #pragma unroll
        for (int f = 0; f < 16; ++f) {
            int nacc = acc + c[f];
            bool hit = (!found) && (g < nacc);
            frag = hit ? f : frag;
            off  = hit ? g - acc : off;
            found = found || hit;
            acc = nacc;
        }
        int sid = sorted16[((slab * NCHUNK + frag) * NTYPE + tt) * CAP + off];
        int e = (slab * SLAB_EL + sid) & (NEL - 1);   // poison-proof

        int k = e & 63, j = (e >> 6) & 63, i = (e >> 12) & 63;
        int i1 = (i + 1) & 63, j1 = (j + 1) & 63;

        // 4 k-pair loads: corner m (dk=0) and m+4 (dk=1) in one 16 B read
        float Ue[24];
        #pragma unroll
        for (int m = 0; m < 4; ++m) {
            int ci = (m & 1) ? i1 : i;        // nodes order: bit0 -> i-offset
            int cj = (m & 2) ? j1 : j;        //              bit1 -> j-offset
            uv4 v = *(const uv4_a8*)(U4hp + (ci * 64 + cj) * UPITCH + k);
            union { unsigned u; __half2 h2; } a, bq, cq2, d;
            a.u = v.x; bq.u = v.y; cq2.u = v.z; d.u = v.w;
            Ue[3*m + 0] = __low2float(a.h2);
            Ue[3*m + 1] = __high2float(a.h2);
            Ue[3*m + 2] = __low2float(bq.h2);
            Ue[3*(m+4) + 0] = __low2float(cq2.h2);
            Ue[3*(m+4) + 1] = __high2float(cq2.h2);
            Ue[3*(m+4) + 2] = __low2float(d.h2);
        }

        float rbuf[24];
        #pragma unroll
        for (int cc = 0; cc < 8; ++cc) {     // 3 rows per corner
            float r0 = 0.f, r1 = 0.f, r2 = 0.f;
            #pragma unroll
            for (int qq = 0; qq < 24; ++qq) {
                r0 = fmaf(F[(3*cc + 0) * 24 + qq], Ue[qq], r0);
                r1 = fmaf(F[(3*cc + 1) * 24 + qq], Ue[qq], r1);
                r2 = fmaf(F[(3*cc + 2) * 24 + qq], Ue[qq], r2);
            }
            rbuf[3*cc + 0] = r0;
            rbuf[3*cc + 1] = r1;
            rbuf[3*cc + 2] = r2;
        }
        union { __half2 hh[12]; uint4 ff[3]; } ob;   // 24 halfs = 48 B
        #pragma unroll
        for (int d = 0; d < 12; ++d)
            ob.hh[d] = __floats2half2_rn(rbuf[2*d], rbuf[2*d + 1]);
        uint4* __restrict__ dst = KUe48 + (size_t)e * 3;
        dst[0] = ob.ff[0];
        dst[1] = ob.ff[1];
        dst[2] = ob.ff[2];
    }
}

// K5: 3-D-tiled LDS-staged reduce. 256 blocks x 1024 thr, 71 KB LDS ->
// 2 blocks/CU. Tile = 4i x 8j x 32k nodes; halo box 5x9x33 = 1485 elements
// staged dword-major [12][SE]. Corner c = halfs 3c..3c+2 -> 2 dword reads +
// static half-select. Output restaged via LDS for coalesced float4 stores.
__global__ __launch_bounds__(1024) void k5_reduce(
    const uint4* __restrict__ KUe48, float* __restrict__ out)
{
    extern __shared__ unsigned cache[];   // [12][SE] dword-major
    int tid = threadIdx.x;
    int b = blockIdx.x;                // 256 blocks
    int slab  = (b & 7) + 8 * (b >> 7);
    int inner = (b >> 3) & 15;
    int i0 = slab * 4;
    int j0 = (inner & 7) << 3;
    int k0 = (inner >> 3) << 5;

    for (int f = tid; f < SE * 3; f += 1024) {
        int le = f / 3, s = f - 3 * (f / 3);
        int pi = le / 297;
        int rem = le - pi * 297;
        int pj = rem / 33;
        int pe = rem - pj * 33;
        int ei = (i0 - 1 + pi) & 63;
        int ej = (j0 - 1 + pj) & 63;
        int ek = (k0 - 1 + pe) & 63;
        uint4 v = KUe48[(size_t)IDX(ei, ej, ek) * 3 + s];
        cache[(4*s + 0) * SE + le] = v.x;
        cache[(4*s + 1) * SE + le] = v.y;
        cache[(4*s + 2) * SE + le] = v.z;
        cache[(4*s + 3) * SE + le] = v.w;
    }
    __syncthreads();

    int ii = tid >> 8, jj = (tid >> 5) & 7, kk = tid & 31;  // node in tile
    const int DI[8] = {0,1,0,1,0,1,0,1};
    const int DJ[8] = {0,0,1,1,0,0,1,1};
    const int DK[8] = {0,0,0,0,1,1,1,1};
    float a0 = 0.f, a1 = 0.f, a2 = 0.f;
    #pragma unroll
    for (int c = 0; c < 8; ++c) {
        int pi = ii + 1 - DI[c];
        int pj = jj + 1 - DJ[c];
        int pe = kk + 1 - DK[c];
        int le = pi * 297 + pj * 33 + pe;
        int h0 = 3 * c;                       // first half index (static)
        int d0 = h0 >> 1;
        unsigned w0 = cache[d0 * SE + le];
        unsigned w1 = cache[(d0 + 1) * SE + le];
        union { unsigned u; __half2 h; } x0, x1;
        x0.u = w0; x1.u = w1;
        if ((h0 & 1) == 0) {                  // even corner: lo0,hi0,lo1
            a0 += __low2float(x0.h);
            a1 += __high2float(x0.h);
            a2 += __low2float(x1.h);
        } else {                              // odd corner: hi0,lo1,hi1
            a0 += __high2float(x0.h);
            a1 += __low2float(x1.h);
            a2 += __high2float(x1.h);
        }
    }

    float* fs = (float*)cache;
    __syncthreads();                   // all cache reads done
    fs[3*tid + 0] = a0;
    fs[3*tid + 1] = a1;
    fs[3*tid + 2] = a2;
    __syncthreads();
    if (tid < 768) {
        int r = tid / 24, cq = tid - r * 24;     // r: (ii,jj) row, cq: float4 col
        int rii = r >> 3, rjj = r & 7;
        int n = (i0 + rii) * 4096 + (j0 + rjj) * 64 + k0;
        float4* __restrict__ o4 = (float4*)(out + (size_t)n * 3);
        o4[cq] = ((float4*)fs)[r * 24 + cq];
    }
}

// Fallback (ws too small): round-1 atomic scatter kernel.
__global__ __launch_bounds__(256) void fe_apply_atomic(
    const float* __restrict__ U, const float* __restrict__ rho,
    const float* __restrict__ filters, float* __restrict__ out)
{
    int e = blockIdx.x * blockDim.x + threadIdx.x;
    int k = e & 63, j = (e >> 6) & 63, i = (e >> 12) & 63;
    int i1 = (i + 1) & 63, j1 = (j + 1) & 63, k1 = (k + 1) & 63;
    int nodes[8];
    nodes[0]=IDX(i,j,k);   nodes[1]=IDX(i1,j,k);   nodes[2]=IDX(i,j1,k);   nodes[3]=IDX(i1,j1,k);
    nodes[4]=IDX(i,j,k1);  nodes[5]=IDX(i1,j,k1);  nodes[6]=IDX(i,j1,k1);  nodes[7]=IDX(i1,j1,k1);
    int t = type_of(rho, i, j, k);
    float Ue[24];
    #pragma unroll
    for (int m = 0; m < 8; ++m) {
        int bb = nodes[m] * 3;
        Ue[3*m+0]=U[bb+0]; Ue[3*m+1]=U[bb+1]; Ue[3*m+2]=U[bb+2];
    }
    const float4* Kr = (const float4*)(filters + t * 576);
    #pragma unroll
    for (int r = 0; r < 24; ++r) {
        float a = 0.f;
        #pragma unroll
        for (int q = 0; q < 6; ++q) {
            float4 f = Kr[r*6+q];
            a = fmaf(f.x,Ue[4*q+0],a); a = fmaf(f.y,Ue[4*q+1],a);
            a = fmaf(f.z,Ue[4*q+2],a); a = fmaf(f.w,Ue[4*q+3],a);
        }
        atomicAdd(&out[nodes[r/3]*3 + (r%3)], a);
    }
}

extern "C" void kernel_launch(void* const* d_in, const int* in_sizes, int n_in,
                              void* d_out, int out_size, void* d_ws, size_t ws_size,
                              hipStream_t stream) {
    const float* U       = (const float*)d_in[0];
    const float* rho     = (const float*)d_in[1];
    const float* filters = (const float*)d_in[3];
    float* out = (float*)d_out;

    if (ws_size < WS_NEEDED) {
        hipMemsetAsync(out, 0, (size_t)out_size * sizeof(float), stream);
        fe_apply_atomic<<<dim3(NEL/256), dim3(256), 0, stream>>>(U, rho, filters, out);
        return;
    }

    char* ws = (char*)d_ws;
    uint2*          U4hp     = (uint2*)(ws + WS_U4);
    uint4*          KUe48    = (uint4*)(ws + WS_KUE);
    unsigned short* sorted16 = (unsigned short*)(ws + WS_SORTED);
    int*            cntmat   = (int*)(ws + WS_CNT);

    // allow 71 KB dynamic LDS for k5 (idempotent; not a stream op)
    (void)hipFuncSetAttribute((const void*)k5_reduce,
                              hipFuncAttributeMaxDynamicSharedMemorySize, K5_LDS);

    k1_pack_scatter<<<dim3(256),  dim3(1024), 0,      stream>>>(U, rho, U4hp, sorted16, cntmat);
    k4_apply       <<<dim3(1024), dim3(512),  0,      stream>>>(U4hp, filters, sorted16, cntmat, KUe48);
    k5_reduce      <<<dim3(256),  dim3(1024), K5_LDS, stream>>>(KUe48, out);
}

// Round 22
// 32.585 us; speedup vs baseline: 1.0091x; 1.0091x over previous
//
#include <hip/hip_runtime.h>
#include <hip/hip_fp16.h>

#define NGRID 64
#define NEL (NGRID*NGRID*NGRID)   /* 262144 */
#define IDX(i,j,k) ((((i)*64 + (j)) * 64) + (k))

#define NSLAB    16                /* slab = 4 consecutive i-planes = 16384 elements */
#define SLAB_EL  16384
#define NTYPE    256
#define NCHUNK   16                /* chunks per slab, 1024 elements each */
#define CAP      32                /* per-(chunk,type) bucket capacity; mean 4, >10 sigma */

#define RHO_EL   2176              /* k1 rho tile: 2 i-planes x 17 j x 64 k */

/* k5 tile: 4i x 8j x 32k nodes (1024) <- halo box 5x9x33 = 1485 elements */
#define SE       1485
#define K5_LDS   (12*SE*4)         /* 71280 B: dword-major [12][SE] -> 2 blocks/CU */

/* U4h padded layout [i][j][65]: slot k=64 duplicates k=0 -> k4 loads nodes
   (k, k+1) as ONE 16 B read (8 B aligned; dwordx4 needs only dword align). */
#define UPITCH   65
#define U4P_SZ   ((size_t)64*64*UPITCH*8)   /* 2.03 MB */

// ---- workspace layout (bytes) ----
// KUe48: 24 halfs (48 B) per element, natural element order. 3 x dwordx4
// stores/element, 12 MB total (slab share 0.75 MB -> L2-fit).
#define WS_U4     0                                   // padded fp16 U, 2.03 MB
#define WS_KUE    (WS_U4 + U4P_SZ)                    // NEL*48 B = 12 MB
#define WS_SORTED (WS_KUE + (size_t)NEL*48)           // 256chunks*256types*CAP i32 = 8 MB
#define WS_CNT    (WS_SORTED + (size_t)256*NTYPE*CAP*4) // [slab][type][chunk16] i32 = 256 KB
#define WS_NEEDED (size_t)(WS_CNT + NSLAB*NTYPE*NCHUNK*4)

typedef unsigned uv4 __attribute__((ext_vector_type(4)));
typedef uv4 uv4_a8 __attribute__((aligned(8)));       // clang: lowers vector alignment

__device__ __forceinline__ int type_of(const float* __restrict__ rho, int i, int j, int k) {
    int i1 = (i + 1) & 63, j1 = (j + 1) & 63, k1 = (k + 1) & 63;
    int t = 0;
    t |= (rho[IDX(i,  j,  k )] > 0.5f ? 1 : 0) << 0;
    t |= (rho[IDX(i1, j,  k )] > 0.5f ? 1 : 0) << 4;
    t |= (rho[IDX(i,  j1, k )] > 0.5f ? 1 : 0) << 2;
    t |= (rho[IDX(i1, j1, k )] > 0.5f ? 1 : 0) << 6;
    t |= (rho[IDX(i,  j,  k1)] > 0.5f ? 1 : 0) << 1;
    t |= (rho[IDX(i1, j,  k1)] > 0.5f ? 1 : 0) << 5;
    t |= (rho[IDX(i,  j1, k1)] > 0.5f ? 1 : 0) << 3;
    t |= (rho[IDX(i1, j1, k1)] > 0.5f ? 1 : 0) << 7;
    return t;
}

// K1: 256 blocks x 1024 thr; slab = b&15, chunk = b>>4 (b%8==slab%8 -> XCD
// pinned). Stage rho bits + contiguous 12 KB U slice (coalesced), type from
// LDS, pack U->fp16 into the PADDED U4h (k==0 thread also fills slot 64),
// LDS hist/rank, scatter into the fixed-stride (slab,chunk,type) bucket.
__global__ __launch_bounds__(1024) void k1_pack_scatter(
    const float* __restrict__ U, const float* __restrict__ rho,
    uint2* __restrict__ U4hp, int* __restrict__ sorted, int* __restrict__ cntmat)
{
    __shared__ int lh[NTYPE];
    __shared__ int rb[RHO_EL];     // [2][17][64] occupancy bits
    __shared__ float us[3072];     // block's U slice (1024 el x 3 floats)
    int tid = threadIdx.x;
    int b = blockIdx.x;
    int slab = b & 15, chunk = b >> 4;
    int i  = slab * 4 + (chunk >> 2);
    int j0 = (chunk & 3) << 4;
    if (tid < NTYPE) lh[tid] = 0;

    int base = slab * SLAB_EL + chunk * 1024;
    if (tid < 768)                 // 768 float4 = 12 KB, fully coalesced
        ((float4*)us)[tid] = ((const float4*)(U + (size_t)base * 3))[tid];

    for (int f = tid; f < RHO_EL; f += 1024) {
        int pi = (f >= 1088) ? 1 : 0;        // plane: 0 -> i, 1 -> i+1
        int rem = f - pi * 1088;
        int pj = rem >> 6, kk = rem & 63;
        int ei = (i + pi) & 63;
        int ej = (j0 + pj) & 63;
        rb[f] = rho[IDX(ei, ej, kk)] > 0.5f ? 1 : 0;
    }
    __syncthreads();

    int e = base + tid;
    int k = tid & 63, jj = tid >> 6;         // element = (i, j0+jj, k)
    union { __half2 h; unsigned u; } pxy, pz;
    pxy.h = __floats2half2_rn(us[3*tid + 0], us[3*tid + 1]);
    pz.h  = __floats2half2_rn(us[3*tid + 2], 0.0f);
    int uidx = (i * 64 + (j0 + jj)) * UPITCH + k;
    U4hp[uidx] = make_uint2(pxy.u, pz.u);
    if (k == 0) U4hp[uidx + 64] = make_uint2(pxy.u, pz.u);   // wrap duplicate

    int t = 0;
    #pragma unroll
    for (int di = 0; di < 2; ++di)
        #pragma unroll
        for (int dj = 0; dj < 2; ++dj)
            #pragma unroll
            for (int dk = 0; dk < 2; ++dk)
                t |= rb[di*1088 + (jj + dj)*64 + ((k + dk) & 63)] << (di*4 + dj*2 + dk);

    int rank = atomicAdd(&lh[t], 1);         // LDS-only atomic
    if (rank < CAP)                          // overflow ~impossible (mean 4)
        sorted[((slab * NCHUNK + chunk) * NTYPE + t) * CAP + rank] = e;
    __syncthreads();
    if (tid < NTYPE)
        cntmat[(slab * NTYPE + tid) * NCHUNK + chunk] = lh[tid];
}

// K4: 2048 blocks x 256 thr (4 waves). Wave = (slab, type, half<64>).
// Count row broadcast; lane locates its element among the 16 chunk-fragments.
// 4 x 16 B k-pair gathers; per-corner row-compute; pack 24 halfs -> 3
// dwordx4 stores (48 B). readfirstlane type -> s_load filter path.
__global__ __launch_bounds__(256) void k4_apply(
    const uint2* __restrict__ U4hp, const float* __restrict__ filters,
    const int* __restrict__ sorted, const int* __restrict__ cntmat,
    uint4* __restrict__ KUe48)
{
    int b = blockIdx.x;
    int slab = (b & 7) + 8 * (b >> 10);       // XCD-pinned
    int q    = (b >> 3) & 127;                // 128 blocks/slab -> 2 types each
    int w    = threadIdx.x >> 6;              // wave 0..3
    int tt   = __builtin_amdgcn_readfirstlane(2 * q + (w >> 1));
    int h    = (w & 1);                       // half: elements [h*64, h*64+64)

    const int4* crow = (const int4*)(cntmat + (slab * NTYPE + tt) * NCHUNK);
    int4 c0 = crow[0], c1 = crow[1], c2 = crow[2], c3 = crow[3];
    int c[16] = { c0.x,c0.y,c0.z,c0.w, c1.x,c1.y,c1.z,c1.w,
                  c2.x,c2.y,c2.z,c2.w, c3.x,c3.y,c3.z,c3.w };
    int total = 0;
    #pragma unroll
    for (int f = 0; f < 16; ++f) total += c[f];
    total = __builtin_amdgcn_readfirstlane(total);
    if (total <= h * 64) return;              // whole wave empty

    int g = h * 64 + (threadIdx.x & 63);
    const float* __restrict__ F = filters + tt * 576;   // SGPR base -> s_load

    if (g < total) {
        int acc = 0, frag = 0, off = 0;
        bool found = false;
        #pragma unroll
        for (int f = 0; f < 16; ++f) {
            int nacc = acc + c[f];
            bool hit = (!found) && (g < nacc);
            frag = hit ? f : frag;
            off  = hit ? g - acc : off;
            found = found || hit;
            acc = nacc;
        }
        int e = sorted[((slab * NCHUNK + frag) * NTYPE + tt) * CAP + off];
        e &= (NEL - 1);                       // defensive: poison-proof addressing

        int k = e & 63, j = (e >> 6) & 63, i = (e >> 12) & 63;
        int i1 = (i + 1) & 63, j1 = (j + 1) & 63;

        // 4 k-pair loads: corner m (dk=0) and m+4 (dk=1) in one 16 B read
        float Ue[24];
        #pragma unroll
        for (int m = 0; m < 4; ++m) {
            int ci = (m & 1) ? i1 : i;        // nodes order: bit0 -> i-offset
            int cj = (m & 2) ? j1 : j;        //              bit1 -> j-offset
            uv4 v = *(const uv4_a8*)(U4hp + (ci * 64 + cj) * UPITCH + k);
            union { unsigned u; __half2 h2; } a, bq, cq2, d;
            a.u = v.x; bq.u = v.y; cq2.u = v.z; d.u = v.w;
            Ue[3*m + 0] = __low2float(a.h2);
            Ue[3*m + 1] = __high2float(a.h2);
            Ue[3*m + 2] = __low2float(bq.h2);
            Ue[3*(m+4) + 0] = __low2float(cq2.h2);
            Ue[3*(m+4) + 1] = __high2float(cq2.h2);
            Ue[3*(m+4) + 2] = __low2float(d.h2);
        }

        float rbuf[24];
        #pragma unroll
        for (int cc = 0; cc < 8; ++cc) {     // 3 rows per corner
            float r0 = 0.f, r1 = 0.f, r2 = 0.f;
            #pragma unroll
            for (int qq = 0; qq < 24; ++qq) {
                r0 = fmaf(F[(3*cc + 0) * 24 + qq], Ue[qq], r0);
                r1 = fmaf(F[(3*cc + 1) * 24 + qq], Ue[qq], r1);
                r2 = fmaf(F[(3*cc + 2) * 24 + qq], Ue[qq], r2);
            }
            rbuf[3*cc + 0] = r0;
            rbuf[3*cc + 1] = r1;
            rbuf[3*cc + 2] = r2;
        }
        union { __half2 hh[12]; uint4 ff[3]; } ob;   // 24 halfs = 48 B
        #pragma unroll
        for (int d = 0; d < 12; ++d)
            ob.hh[d] = __floats2half2_rn(rbuf[2*d], rbuf[2*d + 1]);
        uint4* __restrict__ dst = KUe48 + (size_t)e * 3;
        dst[0] = ob.ff[0];
        dst[1] = ob.ff[1];
        dst[2] = ob.ff[2];
    }
}

// K5: 3-D-tiled LDS-staged reduce. 256 blocks x 1024 thr, 71 KB LDS ->
// 2 blocks/CU. Tile = 4i x 8j x 32k nodes; halo box 5x9x33 = 1485 elements
// staged dword-major [12][SE]. Corner c = halfs 3c..3c+2 -> 2 dword reads +
// static half-select. Output restaged via LDS for coalesced float4 stores.
__global__ __launch_bounds__(1024) void k5_reduce(
    const uint4* __restrict__ KUe48, float* __restrict__ out)
{
    extern __shared__ unsigned cache[];   // [12][SE] dword-major
    int tid = threadIdx.x;
    int b = blockIdx.x;                // 256 blocks
    int slab  = (b & 7) + 8 * (b >> 7);
    int inner = (b >> 3) & 15;
    int i0 = slab * 4;
    int j0 = (inner & 7) << 3;
    int k0 = (inner >> 3) << 5;

    // stage: 1485 elements x 3 uint4 each
    for (int f = tid; f < SE * 3; f += 1024) {
        int le = f / 3, s = f - 3 * (f / 3);
        int pi = le / 297;
        int rem = le - pi * 297;
        int pj = rem / 33;
        int pe = rem - pj * 33;
        int ei = (i0 - 1 + pi) & 63;
        int ej = (j0 - 1 + pj) & 63;
        int ek = (k0 - 1 + pe) & 63;
        uint4 v = KUe48[(size_t)IDX(ei, ej, ek) * 3 + s];
        cache[(4*s + 0) * SE + le] = v.x;
        cache[(4*s + 1) * SE + le] = v.y;
        cache[(4*s + 2) * SE + le] = v.z;
        cache[(4*s + 3) * SE + le] = v.w;
    }
    __syncthreads();

    int ii = tid >> 8, jj = (tid >> 5) & 7, kk = tid & 31;  // node in tile
    const int DI[8] = {0,1,0,1,0,1,0,1};
    const int DJ[8] = {0,0,1,1,0,0,1,1};
    const int DK[8] = {0,0,0,0,1,1,1,1};
    float a0 = 0.f, a1 = 0.f, a2 = 0.f;
    #pragma unroll
    for (int c = 0; c < 8; ++c) {
        int pi = ii + 1 - DI[c];
        int pj = jj + 1 - DJ[c];
        int pe = kk + 1 - DK[c];
        int le = pi * 297 + pj * 33 + pe;
        int h0 = 3 * c;                       // first half index (static)
        int d0 = h0 >> 1;
        unsigned w0 = cache[d0 * SE + le];
        unsigned w1 = cache[(d0 + 1) * SE + le];
        union { unsigned u; __half2 h; } x0, x1;
        x0.u = w0; x1.u = w1;
        if ((h0 & 1) == 0) {                  // even corner: lo0,hi0,lo1
            a0 += __low2float(x0.h);
            a1 += __high2float(x0.h);
            a2 += __low2float(x1.h);
        } else {                              // odd corner: hi0,lo1,hi1
            a0 += __high2float(x0.h);
            a1 += __low2float(x1.h);
            a2 += __high2float(x1.h);
        }
    }

    // restage -> coalesced float4 stores (24 per 32-node k-row)
    float* fs = (float*)cache;
    __syncthreads();                   // all cache reads done
    fs[3*tid + 0] = a0;
    fs[3*tid + 1] = a1;
    fs[3*tid + 2] = a2;
    __syncthreads();
    if (tid < 768) {
        int r = tid / 24, cq = tid - r * 24;     // r: (ii,jj) row, cq: float4 col
        int rii = r >> 3, rjj = r & 7;
        int n = (i0 + rii) * 4096 + (j0 + rjj) * 64 + k0;
        float4* __restrict__ o4 = (float4*)(out + (size_t)n * 3);
        o4[cq] = ((float4*)fs)[r * 24 + cq];
    }
}

// Fallback (ws too small): round-1 atomic scatter kernel.
__global__ __launch_bounds__(256) void fe_apply_atomic(
    const float* __restrict__ U, const float* __restrict__ rho,
    const float* __restrict__ filters, float* __restrict__ out)
{
    int e = blockIdx.x * blockDim.x + threadIdx.x;
    int k = e & 63, j = (e >> 6) & 63, i = (e >> 12) & 63;
    int i1 = (i + 1) & 63, j1 = (j + 1) & 63, k1 = (k + 1) & 63;
    int nodes[8];
    nodes[0]=IDX(i,j,k);   nodes[1]=IDX(i1,j,k);   nodes[2]=IDX(i,j1,k);   nodes[3]=IDX(i1,j1,k);
    nodes[4]=IDX(i,j,k1);  nodes[5]=IDX(i1,j,k1);  nodes[6]=IDX(i,j1,k1);  nodes[7]=IDX(i1,j1,k1);
    int t = type_of(rho, i, j, k);
    float Ue[24];
    #pragma unroll
    for (int m = 0; m < 8; ++m) {
        int bb = nodes[m] * 3;
        Ue[3*m+0]=U[bb+0]; Ue[3*m+1]=U[bb+1]; Ue[3*m+2]=U[bb+2];
    }
    const float4* Kr = (const float4*)(filters + t * 576);
    #pragma unroll
    for (int r = 0; r < 24; ++r) {
        float a = 0.f;
        #pragma unroll
        for (int q = 0; q < 6; ++q) {
            float4 f = Kr[r*6+q];
            a = fmaf(f.x,Ue[4*q+0],a); a = fmaf(f.y,Ue[4*q+1],a);
            a = fmaf(f.z,Ue[4*q+2],a); a = fmaf(f.w,Ue[4*q+3],a);
        }
        atomicAdd(&out[nodes[r/3]*3 + (r%3)], a);
    }
}

extern "C" void kernel_launch(void* const* d_in, const int* in_sizes, int n_in,
                              void* d_out, int out_size, void* d_ws, size_t ws_size,
                              hipStream_t stream) {
    const float* U       = (const float*)d_in[0];
    const float* rho     = (const float*)d_in[1];
    const float* filters = (const float*)d_in[3];
    float* out = (float*)d_out;

    if (ws_size < WS_NEEDED) {
        hipMemsetAsync(out, 0, (size_t)out_size * sizeof(float), stream);
        fe_apply_atomic<<<dim3(NEL/256), dim3(256), 0, stream>>>(U, rho, filters, out);
        return;
    }

    char* ws = (char*)d_ws;
    uint2*  U4hp   = (uint2*)(ws + WS_U4);
    uint4*  KUe48  = (uint4*)(ws + WS_KUE);
    int*    sorted = (int*)(ws + WS_SORTED);
    int*    cntmat = (int*)(ws + WS_CNT);

    // allow 71 KB dynamic LDS for k5 (idempotent; not a stream op)
    (void)hipFuncSetAttribute((const void*)k5_reduce,
                              hipFuncAttributeMaxDynamicSharedMemorySize, K5_LDS);

    k1_pack_scatter<<<dim3(256),  dim3(1024), 0,      stream>>>(U, rho, U4hp, sorted, cntmat);
    k4_apply       <<<dim3(2048), dim3(256),  0,      stream>>>(U4hp, filters, sorted, cntmat, KUe48);
    k5_reduce      <<<dim3(256),  dim3(1024), K5_LDS, stream>>>(KUe48, out);
}